// Round 1
// baseline (1547.815 us; speedup 1.0000x reference)
//
#include <hip/hip_runtime.h>
#include <math.h>

#define BATCH 16
#define CIN 103
#define CCONV 256
#define NOUT 103
#define DOUT 16
#define RECSZ 8343
#define H1SZ 5562
#define H2SZ 12514

// ws float offsets
#define WS_P      0         // 16*256
#define WS_SQ     4096      // 16*256
#define WS_WSUM   8192      // 256*103*16 = 421888
#define WS_BB     430080    // 103*256 = 26368
#define WS_S      456448    // 16*103*16 = 26368
#define WS_FACTOR 482816    // 256
#define WS_F0     483072    // 16*1648 = 26368
#define WS_F1     509440    // 16*5562 = 88992
#define WS_F2     598432    // 16*12514 = 200224
// total = 798656 floats = 3.05 MB

// ---------------- init: biases into accumulators, bb = 1 ----------------
__global__ __launch_bounds__(256) void init_k(float* __restrict__ f1, const float* __restrict__ b1,
                                              float* __restrict__ f2, const float* __restrict__ b2,
                                              float* __restrict__ f3, const float* __restrict__ b3,
                                              float* __restrict__ bb) {
    int i = blockIdx.x * 256 + threadIdx.x;
    if (i < 16 * H1SZ) { f1[i] = b1[i % H1SZ]; return; }
    i -= 16 * H1SZ;
    if (i < 16 * H2SZ) { f2[i] = b2[i % H2SZ]; return; }
    i -= 16 * H2SZ;
    if (i < 16 * RECSZ) { f3[i] = b3[i % RECSZ]; return; }
    i -= 16 * RECSZ;
    if (i < 103 * 256) bb[i] = 1.0f;
}

// ---------------- conv (VALID 3x3) + relu + mean pool -> p[b][co] ----------------
// grid: 16 b * 64 co-groups of 4; block 256 = 4 waves, wave w handles co = cob + w
__global__ __launch_bounds__(256) void conv_pool_k(const float* __restrict__ x,
                                                   const float* __restrict__ w,
                                                   const float* __restrict__ cb,
                                                   float* __restrict__ p) {
    int b = blockIdx.x >> 6;
    int cob = (blockIdx.x & 63) << 2;
    __shared__ float xs[CIN * 81];
    int t = threadIdx.x;
    for (int i = t; i < CIN * 81; i += 256) xs[i] = x[(size_t)b * CIN * 81 + i];
    __syncthreads();
    int wave = t >> 6, lane = t & 63;
    int co = cob + wave;
    co = __builtin_amdgcn_readfirstlane(co);
    int pos = lane < 49 ? lane : 0;
    int oh = pos / 7, ow = pos % 7;
    const float* wp = w + (size_t)co * CIN * 9;
    const float* xp = xs + oh * 9 + ow;
    float acc = 0.f;
    for (int ci = 0; ci < CIN; ++ci) {
#pragma unroll
        for (int kh = 0; kh < 3; ++kh)
#pragma unroll
            for (int kw = 0; kw < 3; ++kw)
                acc = fmaf(xp[ci * 81 + kh * 9 + kw], wp[ci * 9 + kh * 3 + kw], acc);
    }
    acc += cb[co];
    acc = fmaxf(acc, 0.f);
    if (lane >= 49) acc = 0.f;
#pragma unroll
    for (int off = 32; off; off >>= 1) acc += __shfl_down(acc, off);
    if (lane == 0) p[b * 256 + co] = acc * (1.0f / 49.0f);
}

// ---------------- squash p over c -> sq[b][c] ----------------
__global__ __launch_bounds__(256) void squash_p_k(const float* __restrict__ p, float* __restrict__ sq) {
    int b = blockIdx.x, c = threadIdx.x;
    float v = p[b * 256 + c];
    float ss = v * v;
#pragma unroll
    for (int off = 32; off; off >>= 1) ss += __shfl_down(ss, off);
    __shared__ float red[4];
    if ((c & 63) == 0) red[c >> 6] = ss;
    __syncthreads();
    float ms = red[0] + red[1] + red[2] + red[3];
    float mag = sqrtf(ms);
    sq[b * 256 + c] = v * mag / (1.f + ms);
}

// ---------------- Wsum[c][j][o] = sum_i W_caps[c][j][o][i] ----------------
__global__ __launch_bounds__(256) void wsum_k(const float* __restrict__ Wc, float* __restrict__ wsum) {
    int idx = blockIdx.x * 256 + threadIdx.x;   // grid sized exactly 421888
    const float4* p4 = (const float4*)(Wc + (size_t)idx * 32);
    float s = 0.f;
#pragma unroll
    for (int q = 0; q < 8; ++q) { float4 v = p4[q]; s += v.x + v.y + v.z + v.w; }
    wsum[idx] = s;
}

// ---------------- routing: softmax over c + s[b][j][o] ----------------
// grid 103 (j), block 256
__global__ __launch_bounds__(256) void route_s_k(const float* __restrict__ sq,
                                                 const float* __restrict__ wsum,
                                                 const float* __restrict__ bb,
                                                 float* __restrict__ s_out) {
    int j = blockIdx.x;
    int t = threadIdx.x;             // t = c for softmax phase
    __shared__ float sqst[4096];     // [c][b] transposed (conflict-free)
    __shared__ float wls[4096];      // [c][o]
    __shared__ float cc[256];
    __shared__ float red[8];
    float bv = bb[j * 256 + t];
    for (int i = t; i < 4096; i += 256) {
        sqst[i] = sq[((i & 15) << 8) + (i >> 4)];
        wls[i] = wsum[(size_t)(i >> 4) * (103 * 16) + j * 16 + (i & 15)];
    }
    int wave = t >> 6, lane = t & 63;
    float m = bv;
#pragma unroll
    for (int off = 32; off; off >>= 1) m = fmaxf(m, __shfl_down(m, off));
    if (lane == 0) red[wave] = m;
    __syncthreads();
    m = fmaxf(fmaxf(red[0], red[1]), fmaxf(red[2], red[3]));
    float e = expf(bv - m);
    float ssum = e;
#pragma unroll
    for (int off = 32; off; off >>= 1) ssum += __shfl_down(ssum, off);
    if (lane == 0) red[4 + wave] = ssum;
    __syncthreads();
    ssum = red[4] + red[5] + red[6] + red[7];
    cc[t] = e / ssum;
    __syncthreads();
    for (int i = t; i < 4096; i += 256) sqst[i] *= cc[i >> 4];
    __syncthreads();
    int b = t >> 4, o = t & 15;      // t = (b,o) for s phase
    float acc = 0.f;
    for (int c = 0; c < 256; ++c)
        acc = fmaf(sqst[c * 16 + b], wls[c * 16 + o], acc);
    s_out[((size_t)b * 103 + j) * 16 + o] = acc;
}

// ---------------- squash factor over j: factor[b][o] ----------------
__global__ __launch_bounds__(256) void factor_k(const float* __restrict__ s, float* __restrict__ factor) {
    int t = threadIdx.x;
    int b = t >> 4, o = t & 15;
    float ms = 0.f;
    for (int j = 0; j < 103; ++j) {
        float v = s[((size_t)b * 103 + j) * 16 + o];
        ms = fmaf(v, v, ms);
    }
    factor[t] = sqrtf(ms) / (1.f + ms);
}

// ---------------- agreement + bb update ----------------
// grid 103 (j), block 256 (c)
__global__ __launch_bounds__(256) void route_upd_k(const float* __restrict__ sq,
                                                   const float* __restrict__ wsum,
                                                   const float* __restrict__ s,
                                                   const float* __restrict__ factor,
                                                   float* __restrict__ bb) {
    int j = blockIdx.x;
    int t = threadIdx.x;             // = c
    __shared__ float vs[256];        // v[b][o]
    {
        int b = t >> 4, o = t & 15;
        vs[t] = s[((size_t)b * 103 + j) * 16 + o] * factor[t];
    }
    __syncthreads();
    const float4* wp = (const float4*)(wsum + ((size_t)t * 103 + j) * 16);
    float4 w0 = wp[0], w1 = wp[1], w2 = wp[2], w3 = wp[3];
    float wv[16] = {w0.x, w0.y, w0.z, w0.w, w1.x, w1.y, w1.z, w1.w,
                    w2.x, w2.y, w2.z, w2.w, w3.x, w3.y, w3.z, w3.w};
    float acc = 0.f;
#pragma unroll
    for (int b = 0; b < 16; ++b) {
        float d = 0.f;
#pragma unroll
        for (int o = 0; o < 16; ++o) d = fmaf(wv[o], vs[b * 16 + o], d);
        acc = fmaf(sq[b * 256 + t], d, acc);
    }
    bb[j * 256 + t] += acc * (1.0f / 16.0f);
}

// ---------------- final v, ba output, f0 = v*ba ----------------
__global__ __launch_bounds__(256) void final_v_k(const float* __restrict__ s,
                                                 const float* __restrict__ factor,
                                                 float* __restrict__ out_ba,
                                                 float* __restrict__ f0) {
    int idx = blockIdx.x * 256 + threadIdx.x;   // = b*103 + j
    if (idx >= 16 * 103) return;
    int b = idx / 103;
    const float4* sp = (const float4*)(s + (size_t)idx * 16);
    float4 s0 = sp[0], s1 = sp[1], s2 = sp[2], s3 = sp[3];
    float sv[16] = {s0.x, s0.y, s0.z, s0.w, s1.x, s1.y, s1.z, s1.w,
                    s2.x, s2.y, s2.z, s2.w, s3.x, s3.y, s3.z, s3.w};
    float v[16];
    float nrm2 = 0.f;
#pragma unroll
    for (int o = 0; o < 16; ++o) {
        v[o] = sv[o] * factor[b * 16 + o];
        nrm2 = fmaf(v[o], v[o], nrm2);
    }
    float ba = sqrtf(nrm2);
    out_ba[idx] = ba;
    float4* fp = (float4*)(f0 + (size_t)idx * 16);
    float4 r0 = {v[0] * ba, v[1] * ba, v[2] * ba, v[3] * ba};
    float4 r1 = {v[4] * ba, v[5] * ba, v[6] * ba, v[7] * ba};
    float4 r2 = {v[8] * ba, v[9] * ba, v[10] * ba, v[11] * ba};
    float4 r3 = {v[12] * ba, v[13] * ba, v[14] * ba, v[15] * ba};
    fp[0] = r0; fp[1] = r1; fp[2] = r2; fp[3] = r3;
}

// ---------------- FC: out[b][n] += sum_k in[b][k] * w[k][n]  (out pre-set to bias) ----------------
// grid (ceil(N/256), ksplit); block 256; thread per column n
__global__ __launch_bounds__(256) void fc_k(const float* __restrict__ in,
                                            const float* __restrict__ w,
                                            float* __restrict__ out,
                                            int K, int N, int kchunk) {
    int n0 = blockIdx.x * 256 + threadIdx.x;
    int n = n0 < N ? n0 : N - 1;              // clamp: keep loop in uniform CF
    int k0 = blockIdx.y * kchunk;
    int k1 = k0 + kchunk;
    if (k1 > K) k1 = K;
    float acc[16];
#pragma unroll
    for (int b = 0; b < 16; ++b) acc[b] = 0.f;
    for (int k = k0; k < k1; ++k) {
        float wv = w[(size_t)k * N + n];
#pragma unroll
        for (int b = 0; b < 16; ++b)
            acc[b] = fmaf(in[b * K + k], wv, acc[b]);   // in[] addr is wave-uniform -> s_load
    }
    if (n0 < N) {
#pragma unroll
        for (int b = 0; b < 16; ++b) atomicAdd(&out[(size_t)b * N + n], acc[b]);
    }
}

extern "C" void kernel_launch(void* const* d_in, const int* in_sizes, int n_in,
                              void* d_out, int out_size, void* d_ws, size_t ws_size,
                              hipStream_t stream) {
    const float* x      = (const float*)d_in[0];
    const float* conv_w = (const float*)d_in[1];
    const float* conv_b = (const float*)d_in[2];
    const float* W_caps = (const float*)d_in[3];
    const float* fc1_w  = (const float*)d_in[4];
    const float* fc1_b  = (const float*)d_in[5];
    const float* fc2_w  = (const float*)d_in[6];
    const float* fc2_b  = (const float*)d_in[7];
    const float* fc3_w  = (const float*)d_in[8];
    const float* fc3_b  = (const float*)d_in[9];
    float* out = (float*)d_out;
    float* ws  = (float*)d_ws;

    float* p      = ws + WS_P;
    float* sq     = ws + WS_SQ;
    float* wsum   = ws + WS_WSUM;
    float* bb     = ws + WS_BB;
    float* s      = ws + WS_S;
    float* factor = ws + WS_FACTOR;
    float* f0     = ws + WS_F0;
    float* f1     = ws + WS_F1;
    float* f2     = ws + WS_F2;
    float* ba_out = out;            // 1648
    float* recon  = out + 1648;     // 133488 (= f3 accumulator)

    // init accumulators with biases, bb with 1.0  (total 449072 elems)
    init_k<<<1755, 256, 0, stream>>>(f1, fc1_b, f2, fc2_b, recon, fc3_b, bb);

    conv_pool_k<<<1024, 256, 0, stream>>>(x, conv_w, conv_b, p);
    squash_p_k<<<16, 256, 0, stream>>>(p, sq);
    wsum_k<<<1648, 256, 0, stream>>>(W_caps, wsum);   // 1648*256 == 421888 exactly

    for (int it = 0; it < 3; ++it) {
        route_s_k<<<103, 256, 0, stream>>>(sq, wsum, bb, s);
        factor_k<<<1, 256, 0, stream>>>(s, factor);
        if (it < 2)
            route_upd_k<<<103, 256, 0, stream>>>(sq, wsum, s, factor, bb);
    }
    final_v_k<<<7, 256, 0, stream>>>(s, factor, ba_out, f0);

    // fc1: (16,1648)@(1648,5562) ; kchunk*ksplit >= K
    fc_k<<<dim3(22, 8),  256, 0, stream>>>(f0, fc1_w, f1,    1648,  H1SZ, 206);
    // fc2: (16,5562)@(5562,12514)
    fc_k<<<dim3(49, 16), 256, 0, stream>>>(f1, fc2_w, f2,    H1SZ,  H2SZ, 348);
    // fc3: (16,12514)@(12514,8343) -> recon
    fc_k<<<dim3(33, 24), 256, 0, stream>>>(f2, fc3_w, recon, H2SZ,  RECSZ, 522);
}

// Round 2
// 1069.133 us; speedup vs baseline: 1.4477x; 1.4477x over previous
//
#include <hip/hip_runtime.h>
#include <math.h>

#define BATCH 16
#define CIN 103
#define CCONV 256
#define NOUT 103
#define DOUT 16
#define RECSZ 8343
#define H1SZ 5562
#define H2SZ 12514

// ws float offsets
#define WS_P      0         // 16*256
#define WS_SQ     4096      // 16*256
#define WS_WSUM   8192      // 256*103*16 = 421888
#define WS_BB     430080    // 103*256 = 26368
#define WS_S      456448    // 16*103*16 = 26368
#define WS_FACTOR 482816    // 256
#define WS_F0     483072    // 16*1648 = 26368
#define WS_F1     509440    // 16*5562 = 88992
#define WS_F2     598432    // 16*12514 = 200224
// total = 798656 floats = 3.05 MB

// ---------------- init: biases into accumulators, bb = 1 ----------------
__global__ __launch_bounds__(256) void init_k(float* __restrict__ f1, const float* __restrict__ b1,
                                              float* __restrict__ f2, const float* __restrict__ b2,
                                              float* __restrict__ f3, const float* __restrict__ b3,
                                              float* __restrict__ bb) {
    int i = blockIdx.x * 256 + threadIdx.x;
    if (i < 16 * H1SZ) { f1[i] = b1[i % H1SZ]; return; }
    i -= 16 * H1SZ;
    if (i < 16 * H2SZ) { f2[i] = b2[i % H2SZ]; return; }
    i -= 16 * H2SZ;
    if (i < 16 * RECSZ) { f3[i] = b3[i % RECSZ]; return; }
    i -= 16 * RECSZ;
    if (i < 103 * 256) bb[i] = 1.0f;
}

// ---------------- conv (VALID 3x3) + relu + mean pool -> p[b][co] ----------------
__global__ __launch_bounds__(256) void conv_pool_k(const float* __restrict__ x,
                                                   const float* __restrict__ w,
                                                   const float* __restrict__ cb,
                                                   float* __restrict__ p) {
    int b = blockIdx.x >> 6;
    int cob = (blockIdx.x & 63) << 2;
    __shared__ float xs[CIN * 81];
    int t = threadIdx.x;
    for (int i = t; i < CIN * 81; i += 256) xs[i] = x[(size_t)b * CIN * 81 + i];
    __syncthreads();
    int wave = t >> 6, lane = t & 63;
    int co = cob + wave;
    co = __builtin_amdgcn_readfirstlane(co);
    int pos = lane < 49 ? lane : 0;
    int oh = pos / 7, ow = pos % 7;
    const float* wp = w + (size_t)co * CIN * 9;
    const float* xp = xs + oh * 9 + ow;
    float acc = 0.f;
    for (int ci = 0; ci < CIN; ++ci) {
#pragma unroll
        for (int kh = 0; kh < 3; ++kh)
#pragma unroll
            for (int kw = 0; kw < 3; ++kw)
                acc = fmaf(xp[ci * 81 + kh * 9 + kw], wp[ci * 9 + kh * 3 + kw], acc);
    }
    acc += cb[co];
    acc = fmaxf(acc, 0.f);
    if (lane >= 49) acc = 0.f;
#pragma unroll
    for (int off = 32; off; off >>= 1) acc += __shfl_down(acc, off);
    if (lane == 0) p[b * 256 + co] = acc * (1.0f / 49.0f);
}

// ---------------- squash p over c -> sq[b][c] ----------------
__global__ __launch_bounds__(256) void squash_p_k(const float* __restrict__ p, float* __restrict__ sq) {
    int b = blockIdx.x, c = threadIdx.x;
    float v = p[b * 256 + c];
    float ss = v * v;
#pragma unroll
    for (int off = 32; off; off >>= 1) ss += __shfl_down(ss, off);
    __shared__ float red[4];
    if ((c & 63) == 0) red[c >> 6] = ss;
    __syncthreads();
    float ms = red[0] + red[1] + red[2] + red[3];
    float mag = sqrtf(ms);
    sq[b * 256 + c] = v * mag / (1.f + ms);
}

// ---------------- Wsum[c][j][o] = sum_i W_caps[c][j][o][i] ----------------
__global__ __launch_bounds__(256) void wsum_k(const float* __restrict__ Wc, float* __restrict__ wsum) {
    int idx = blockIdx.x * 256 + threadIdx.x;
    const float4* p4 = (const float4*)(Wc + (size_t)idx * 32);
    float s = 0.f;
#pragma unroll
    for (int q = 0; q < 8; ++q) { float4 v = p4[q]; s += v.x + v.y + v.z + v.w; }
    wsum[idx] = s;
}

// ---------------- routing: softmax over c + s[b][j][o] ----------------
__global__ __launch_bounds__(256) void route_s_k(const float* __restrict__ sq,
                                                 const float* __restrict__ wsum,
                                                 const float* __restrict__ bb,
                                                 float* __restrict__ s_out) {
    int j = blockIdx.x;
    int t = threadIdx.x;
    __shared__ float sqst[4096];
    __shared__ float wls[4096];
    __shared__ float cc[256];
    __shared__ float red[8];
    float bv = bb[j * 256 + t];
    for (int i = t; i < 4096; i += 256) {
        sqst[i] = sq[((i & 15) << 8) + (i >> 4)];
        wls[i] = wsum[(size_t)(i >> 4) * (103 * 16) + j * 16 + (i & 15)];
    }
    int wave = t >> 6, lane = t & 63;
    float m = bv;
#pragma unroll
    for (int off = 32; off; off >>= 1) m = fmaxf(m, __shfl_down(m, off));
    if (lane == 0) red[wave] = m;
    __syncthreads();
    m = fmaxf(fmaxf(red[0], red[1]), fmaxf(red[2], red[3]));
    float e = expf(bv - m);
    float ssum = e;
#pragma unroll
    for (int off = 32; off; off >>= 1) ssum += __shfl_down(ssum, off);
    if (lane == 0) red[4 + wave] = ssum;
    __syncthreads();
    ssum = red[4] + red[5] + red[6] + red[7];
    cc[t] = e / ssum;
    __syncthreads();
    for (int i = t; i < 4096; i += 256) sqst[i] *= cc[i >> 4];
    __syncthreads();
    int b = t >> 4, o = t & 15;
    float acc = 0.f;
    for (int c = 0; c < 256; ++c)
        acc = fmaf(sqst[c * 16 + b], wls[c * 16 + o], acc);
    s_out[((size_t)b * 103 + j) * 16 + o] = acc;
}

// ---------------- squash factor over j: factor[b][o] ----------------
__global__ __launch_bounds__(256) void factor_k(const float* __restrict__ s, float* __restrict__ factor) {
    int t = threadIdx.x;
    int b = t >> 4, o = t & 15;
    float ms = 0.f;
    for (int j = 0; j < 103; ++j) {
        float v = s[((size_t)b * 103 + j) * 16 + o];
        ms = fmaf(v, v, ms);
    }
    factor[t] = sqrtf(ms) / (1.f + ms);
}

// ---------------- agreement + bb update ----------------
__global__ __launch_bounds__(256) void route_upd_k(const float* __restrict__ sq,
                                                   const float* __restrict__ wsum,
                                                   const float* __restrict__ s,
                                                   const float* __restrict__ factor,
                                                   float* __restrict__ bb) {
    int j = blockIdx.x;
    int t = threadIdx.x;
    __shared__ float vs[256];
    {
        int b = t >> 4, o = t & 15;
        vs[t] = s[((size_t)b * 103 + j) * 16 + o] * factor[t];
    }
    __syncthreads();
    const float4* wp = (const float4*)(wsum + ((size_t)t * 103 + j) * 16);
    float4 w0 = wp[0], w1 = wp[1], w2 = wp[2], w3 = wp[3];
    float wv[16] = {w0.x, w0.y, w0.z, w0.w, w1.x, w1.y, w1.z, w1.w,
                    w2.x, w2.y, w2.z, w2.w, w3.x, w3.y, w3.z, w3.w};
    float acc = 0.f;
#pragma unroll
    for (int b = 0; b < 16; ++b) {
        float d = 0.f;
#pragma unroll
        for (int o = 0; o < 16; ++o) d = fmaf(wv[o], vs[b * 16 + o], d);
        acc = fmaf(sq[b * 256 + t], d, acc);
    }
    bb[j * 256 + t] += acc * (1.0f / 16.0f);
}

// ---------------- final v, ba output, f0 = v*ba ----------------
__global__ __launch_bounds__(256) void final_v_k(const float* __restrict__ s,
                                                 const float* __restrict__ factor,
                                                 float* __restrict__ out_ba,
                                                 float* __restrict__ f0) {
    int idx = blockIdx.x * 256 + threadIdx.x;
    if (idx >= 16 * 103) return;
    int b = idx / 103;
    const float4* sp = (const float4*)(s + (size_t)idx * 16);
    float4 s0 = sp[0], s1 = sp[1], s2 = sp[2], s3 = sp[3];
    float sv[16] = {s0.x, s0.y, s0.z, s0.w, s1.x, s1.y, s1.z, s1.w,
                    s2.x, s2.y, s2.z, s2.w, s3.x, s3.y, s3.z, s3.w};
    float v[16];
    float nrm2 = 0.f;
#pragma unroll
    for (int o = 0; o < 16; ++o) {
        v[o] = sv[o] * factor[b * 16 + o];
        nrm2 = fmaf(v[o], v[o], nrm2);
    }
    float ba = sqrtf(nrm2);
    out_ba[idx] = ba;
    float4* fp = (float4*)(f0 + (size_t)idx * 16);
    float4 r0 = {v[0] * ba, v[1] * ba, v[2] * ba, v[3] * ba};
    float4 r1 = {v[4] * ba, v[5] * ba, v[6] * ba, v[7] * ba};
    float4 r2 = {v[8] * ba, v[9] * ba, v[10] * ba, v[11] * ba};
    float4 r3 = {v[12] * ba, v[13] * ba, v[14] * ba, v[15] * ba};
    fp[0] = r0; fp[1] = r1; fp[2] = r2; fp[3] = r3;
}

// ---------------- FC: out[b][n] += sum_k in[b][k] * w[k][n]  (out pre-set to bias) ----------------
// Thread handles 2 adjacent columns. Activation chunk staged in LDS ([k][b] layout,
// wave-uniform broadcast reads). k-unroll x4 for MLP. V2: float2 weight loads
// (requires even N for row alignment); !V2: scalar pair (fc3, N odd).
template <bool V2>
__global__ __launch_bounds__(256) void fc_k(const float* __restrict__ in,
                                            const float* __restrict__ w,
                                            float* __restrict__ out,
                                            int K, int N, int kchunk) {
    extern __shared__ float sact[];   // [nk][16]
    const int k0 = blockIdx.y * kchunk;
    int nk = K - k0; if (nk > kchunk) nk = kchunk;
    for (int i = threadIdx.x; i < (nk << 4); i += 256)
        sact[i] = in[(i & 15) * K + k0 + (i >> 4)];
    __syncthreads();

    const int c0 = blockIdx.x * 512 + (threadIdx.x << 1);
    const bool st0 = c0 < N;
    const bool st1 = c0 + 1 < N;
    const int c = st0 ? c0 : 0;          // clamp OOB threads to col 0 (stores guarded)
    const int off1 = st1 ? 1 : 0;        // odd-N tail: duplicate col (a1 discarded)
    const float* wp = w + (size_t)k0 * N + c;
    const size_t Ns = (size_t)N;

    float a0[16], a1[16];
#pragma unroll
    for (int b = 0; b < 16; ++b) { a0[b] = 0.f; a1[b] = 0.f; }

    int k = 0;
    for (; k + 4 <= nk; k += 4) {
        float w00, w01, w10, w11, w20, w21, w30, w31;
        if (V2) {
            float2 q0 = *(const float2*)(wp);
            float2 q1 = *(const float2*)(wp + Ns);
            float2 q2 = *(const float2*)(wp + 2 * Ns);
            float2 q3 = *(const float2*)(wp + 3 * Ns);
            w00 = q0.x; w01 = q0.y; w10 = q1.x; w11 = q1.y;
            w20 = q2.x; w21 = q2.y; w30 = q3.x; w31 = q3.y;
        } else {
            w00 = wp[0];          w01 = wp[off1];
            w10 = wp[Ns];         w11 = wp[Ns + off1];
            w20 = wp[2 * Ns];     w21 = wp[2 * Ns + off1];
            w30 = wp[3 * Ns];     w31 = wp[3 * Ns + off1];
        }
        wp += 4 * Ns;
        const float* s0 = sact + (k << 4);
#pragma unroll
        for (int b = 0; b < 16; ++b) {
            float v0 = s0[b], v1 = s0[16 + b], v2 = s0[32 + b], v3 = s0[48 + b];
            a0[b] = fmaf(v0, w00, a0[b]);
            a1[b] = fmaf(v0, w01, a1[b]);
            a0[b] = fmaf(v1, w10, a0[b]);
            a1[b] = fmaf(v1, w11, a1[b]);
            a0[b] = fmaf(v2, w20, a0[b]);
            a1[b] = fmaf(v2, w21, a1[b]);
            a0[b] = fmaf(v3, w30, a0[b]);
            a1[b] = fmaf(v3, w31, a1[b]);
        }
    }
    for (; k < nk; ++k) {
        float wv0, wv1;
        if (V2) { float2 q = *(const float2*)(wp); wv0 = q.x; wv1 = q.y; }
        else    { wv0 = wp[0]; wv1 = wp[off1]; }
        wp += Ns;
        const float* s0 = sact + (k << 4);
#pragma unroll
        for (int b = 0; b < 16; ++b) {
            a0[b] = fmaf(s0[b], wv0, a0[b]);
            a1[b] = fmaf(s0[b], wv1, a1[b]);
        }
    }
    if (st0) {
#pragma unroll
        for (int b = 0; b < 16; ++b) atomicAdd(&out[b * Ns + c], a0[b]);
    }
    if (st1) {
#pragma unroll
        for (int b = 0; b < 16; ++b) atomicAdd(&out[b * Ns + c + 1], a1[b]);
    }
}

extern "C" void kernel_launch(void* const* d_in, const int* in_sizes, int n_in,
                              void* d_out, int out_size, void* d_ws, size_t ws_size,
                              hipStream_t stream) {
    const float* x      = (const float*)d_in[0];
    const float* conv_w = (const float*)d_in[1];
    const float* conv_b = (const float*)d_in[2];
    const float* W_caps = (const float*)d_in[3];
    const float* fc1_w  = (const float*)d_in[4];
    const float* fc1_b  = (const float*)d_in[5];
    const float* fc2_w  = (const float*)d_in[6];
    const float* fc2_b  = (const float*)d_in[7];
    const float* fc3_w  = (const float*)d_in[8];
    const float* fc3_b  = (const float*)d_in[9];
    float* out = (float*)d_out;
    float* ws  = (float*)d_ws;

    float* p      = ws + WS_P;
    float* sq     = ws + WS_SQ;
    float* wsum   = ws + WS_WSUM;
    float* bb     = ws + WS_BB;
    float* s      = ws + WS_S;
    float* factor = ws + WS_FACTOR;
    float* f0     = ws + WS_F0;
    float* f1     = ws + WS_F1;
    float* f2     = ws + WS_F2;
    float* ba_out = out;            // 1648
    float* recon  = out + 1648;     // 133488

    init_k<<<1755, 256, 0, stream>>>(f1, fc1_b, f2, fc2_b, recon, fc3_b, bb);

    conv_pool_k<<<1024, 256, 0, stream>>>(x, conv_w, conv_b, p);
    squash_p_k<<<16, 256, 0, stream>>>(p, sq);
    wsum_k<<<1648, 256, 0, stream>>>(W_caps, wsum);

    for (int it = 0; it < 3; ++it) {
        route_s_k<<<103, 256, 0, stream>>>(sq, wsum, bb, s);
        factor_k<<<1, 256, 0, stream>>>(s, factor);
        if (it < 2)
            route_upd_k<<<103, 256, 0, stream>>>(sq, wsum, s, factor, bb);
    }
    final_v_k<<<7, 256, 0, stream>>>(s, factor, ba_out, f0);

    // fc1: (16,1648)@(1648,5562), even N -> float2 path
    fc_k<true><<<dim3(11, 46), 256, 36 * 16 * 4, stream>>>(f0, fc1_w, f1, 1648, H1SZ, 36);
    // fc2: (16,5562)@(5562,12514), even N -> float2 path
    fc_k<true><<<dim3(25, 20), 256, 279 * 16 * 4, stream>>>(f1, fc2_w, f2, H1SZ, H2SZ, 279);
    // fc3: (16,12514)@(12514,8343), odd N -> scalar-pair path
    fc_k<false><<<dim3(17, 30), 256, 418 * 16 * 4, stream>>>(f2, fc3_w, recon, H2SZ, RECSZ, 418);
}